// Round 9
// baseline (423.814 us; speedup 1.0000x reference)
//
#include <hip/hip_runtime.h>

// GCN rank-1 collapse + 2-level counting-sort partition (R14b).
// R8-round failure diagnosed as a REAL kernel hang (not infra): degout2's
// dbEnd=(g+1)*GS was never clamped to NB -> OOB curC read -> garbage hi ->
// (i1-lo) underflow -> ~4e9-iteration OOB loop -> GPU hang. Fixed: NB param
// + clamp. Design unchanged from R14:
// R13 post-mortem: wh pinned ~61-73us across L2-gather / LDS-staged /
// L1-gather -> bottleneck is TA line-serialization (~60 line reqs per
// 64-lane random gather, ~1/cyc/CU, same for L1/L2 hits). Only LDS does
// parallel random access. R12's LDS-gather failed on occupancy (64KB,34%).
// R14: 4096-node src-blocks (BSH2=12) -> 16KB slice; wh2s LDS = 48KB ->
// 3 blocks/CU (75% occ); GNUM=12 -> 744 blocks. 128-bucket two-wave scan
// in subsort. Degrees: row kernel (din) + column kernel (dout), u16
// partials aliased in dead dstP region.

#define TB 256
#define DTB 512
#define STB 512
#define BSH 13
#define BNODES 8192
#define BSH2 12
#define SNODES 4096
#define MAXNB 64
#define MAXSB 128
#define SCH 4096
#define SCH4 (SCH / 4)
#define SCH2 4096
#define EPT 8
#define CSTR 16
#define GNUM 12
#define GOUT 6
#define INVB 0xFFFFFFFFu

typedef __attribute__((ext_vector_type(4))) int int4v;
typedef __attribute__((ext_vector_type(4))) unsigned uint4v;
typedef __attribute__((ext_vector_type(4))) float float4v;

__global__ void init_kernel(unsigned* __restrict__ curD, unsigned* __restrict__ curS,
                            unsigned* __restrict__ curC, float* __restrict__ Xsum,
                            int NB, unsigned CAP, int cells, unsigned CAP2, int G) {
    int i = blockIdx.x * TB + threadIdx.x;
    if (i < NB) curD[i * CSTR] = (unsigned)i * CAP;
    if (curS && i < NB) curS[i * CSTR] = (unsigned)i * CAP;
    if (curC && i < cells) curC[i * CSTR] = (unsigned)i * CAP2;
    if (i < G) Xsum[i] = 0.0f;
}

// Level-1: partition edges by dst-block. srcP==nullptr -> 2D mode (no S side).
__global__ void scatter_sort_kernel(const int* __restrict__ src, const int* __restrict__ dst,
                                    unsigned* __restrict__ curD, unsigned* __restrict__ curS,
                                    unsigned* __restrict__ dstP, unsigned short* __restrict__ srcP,
                                    int NB, int E, int blk0) {
    __shared__ unsigned cntD[MAXNB], cntS[MAXNB];
    __shared__ unsigned deltaD[MAXNB], deltaS[MAXNB];
    __shared__ unsigned totD_s, totS_s;
    __shared__ unsigned payD[SCH];
    __shared__ unsigned short valS[SCH];
    __shared__ unsigned char mapD[SCH], mapS[SCH];

    int tid = threadIdx.x;
    if (tid < MAXNB) { cntD[tid] = 0u; cntS[tid] = 0u; }
    __syncthreads();

    unsigned sA[EPT], dA[EPT], bD[EPT], bS[EPT];
    int blk = blockIdx.x + blk0;
#pragma unroll
    for (int v = 0; v < 2; ++v) {
        int q = blk * SCH4 + v * STB + tid;
        int be = q * 4;
        if (be + 3 < E) {
            int4v s4 = __builtin_nontemporal_load((const int4v*)src + q);
            int4v d4 = __builtin_nontemporal_load((const int4v*)dst + q);
#pragma unroll
            for (int k = 0; k < 4; ++k) {
                sA[v*4+k] = (unsigned)s4[k];
                dA[v*4+k] = (unsigned)d4[k];
                bD[v*4+k] = dA[v*4+k] >> BSH;
                bS[v*4+k] = sA[v*4+k] >> BSH;
            }
        } else {
#pragma unroll
            for (int k = 0; k < 4; ++k) {
                int j = be + k;
                if (j < E) {
                    sA[v*4+k] = (unsigned)src[j];
                    dA[v*4+k] = (unsigned)dst[j];
                    bD[v*4+k] = dA[v*4+k] >> BSH;
                    bS[v*4+k] = sA[v*4+k] >> BSH;
                } else {
                    bD[v*4+k] = INVB; bS[v*4+k] = INVB;
                    sA[v*4+k] = 0u; dA[v*4+k] = 0u;
                }
            }
        }
    }

#pragma unroll
    for (int k = 0; k < EPT; ++k) {
        if (bD[k] != INVB) {
            atomicAdd(&cntD[bD[k]], 1u);
            if (srcP) atomicAdd(&cntS[bS[k]], 1u);
        }
    }
    __syncthreads();

    int wv = tid >> 6, ln = tid & 63;
    if (wv == 0) {
        unsigned x = (ln < NB) ? cntD[ln] : 0u;
        unsigned inc = x;
#pragma unroll
        for (int o = 1; o < 64; o <<= 1) {
            unsigned y = __shfl_up(inc, o, 64);
            if (ln >= o) inc += y;
        }
        unsigned exc = inc - x;
        if (ln < NB) {
            unsigned gb = atomicAdd(&curD[ln * CSTR], x);
            deltaD[ln] = gb - exc;
            cntD[ln] = exc;
        }
        if (ln == 63) totD_s = inc;
    } else if (wv == 1 && srcP) {
        unsigned x = (ln < NB) ? cntS[ln] : 0u;
        unsigned inc = x;
#pragma unroll
        for (int o = 1; o < 64; o <<= 1) {
            unsigned y = __shfl_up(inc, o, 64);
            if (ln >= o) inc += y;
        }
        unsigned exc = inc - x;
        if (ln < NB) {
            unsigned gb = atomicAdd(&curS[ln * CSTR], x);
            deltaS[ln] = gb - exc;
            cntS[ln] = exc;
        }
        if (ln == 63) totS_s = inc;
    }
    __syncthreads();

#pragma unroll
    for (int k = 0; k < EPT; ++k) {
        if (bD[k] != INVB) {
            unsigned p = atomicAdd(&cntD[bD[k]], 1u);
            payD[p] = ((dA[k] & (BNODES - 1)) << 19) | sA[k];
            mapD[p] = (unsigned char)bD[k];
            if (srcP) {
                unsigned p2 = atomicAdd(&cntS[bS[k]], 1u);
                valS[p2] = (unsigned short)(sA[k] & (BNODES - 1));
                mapS[p2] = (unsigned char)bS[k];
            }
        }
    }
    __syncthreads();

    unsigned tD = totD_s;
    for (unsigned i = tid; i < tD; i += STB) {
        unsigned b = mapD[i];
        dstP[deltaD[b] + i] = payD[i];
    }
    if (srcP) {
        unsigned tS = totS_s;
        for (unsigned i = tid; i < tS; i += STB) {
            unsigned b = mapS[i];
            srcP[deltaS[b] + i] = valS[i];
        }
    }
}

// Level-2: split each dst-bucket by 4096-node src-block (up to 128 buckets,
// two-wave scan). Payload out: (dst_local:13 << 12) | src_local:12.
__global__ void subsort_kernel(const unsigned* __restrict__ dstP, const unsigned* __restrict__ curD,
                               unsigned* __restrict__ curC, unsigned* __restrict__ dstP2,
                               unsigned CAP, unsigned CAP2, int NSB, int MAXCH) {
    __shared__ unsigned cnt2[MAXSB], delta2[MAXSB];
    __shared__ unsigned wtot[2];
    __shared__ unsigned tot_s;
    __shared__ unsigned pay[SCH2];
    __shared__ unsigned char map2[SCH2];

    int db = blockIdx.x / MAXCH, c = blockIdx.x % MAXCH;
    unsigned s = (unsigned)db * CAP + (unsigned)c * SCH2;
    unsigned e = curD[db * CSTR];            // absolute end of db region
    if (s >= e) return;                      // uniform early-out
    unsigned n = e - s; if (n > SCH2) n = SCH2;

    int tid = threadIdx.x;
    if (tid < MAXSB) cnt2[tid] = 0u;
    __syncthreads();

    unsigned pl[EPT], bk[EPT];
#pragma unroll
    for (int v = 0; v < 2; ++v) {
        unsigned q = (unsigned)(v * STB + tid);
        unsigned base = q * 4u;
        if (base + 3u < n) {
            uint4v p4 = *((const uint4v*)(dstP + s) + q);
#pragma unroll
            for (int k = 0; k < 4; ++k) {
                pl[v*4+k] = p4[k];
                bk[v*4+k] = (p4[k] & 0x7FFFFu) >> BSH2;
            }
        } else {
#pragma unroll
            for (int k = 0; k < 4; ++k) {
                unsigned j = base + (unsigned)k;
                if (j < n) {
                    pl[v*4+k] = dstP[s + j];
                    bk[v*4+k] = (pl[v*4+k] & 0x7FFFFu) >> BSH2;
                } else { bk[v*4+k] = INVB; pl[v*4+k] = 0u; }
            }
        }
    }

#pragma unroll
    for (int k = 0; k < EPT; ++k)
        if (bk[k] != INVB) atomicAdd(&cnt2[bk[k]], 1u);
    __syncthreads();

    unsigned x = 0, inc = 0;
    if (tid < MAXSB) {
        x = cnt2[tid];
        inc = x;
#pragma unroll
        for (int o = 1; o < 64; o <<= 1) {
            unsigned y = __shfl_up(inc, o, 64);
            if ((tid & 63) >= o) inc += y;
        }
        if ((tid & 63) == 63) wtot[tid >> 6] = inc;
    }
    __syncthreads();
    if (tid < MAXSB) {
        unsigned base = (tid >= 64) ? wtot[0] : 0u;
        unsigned exc = inc - x + base;
        if (tid < NSB) {
            unsigned gb = atomicAdd(&curC[((unsigned)db * NSB + tid) * CSTR], x);
            delta2[tid] = gb - exc;
            cnt2[tid] = exc;
        }
        if (tid == MAXSB - 1) tot_s = inc + base;
    }
    __syncthreads();

#pragma unroll
    for (int k = 0; k < EPT; ++k) {
        if (bk[k] != INVB) {
            unsigned p = atomicAdd(&cnt2[bk[k]], 1u);
            pay[p] = ((pl[k] >> 19) << BSH2) | (pl[k] & (SNODES - 1));
            map2[p] = (unsigned char)bk[k];
        }
    }
    __syncthreads();

    unsigned tot = tot_s;
    for (unsigned i = tid; i < tot; i += STB) {
        unsigned b = map2[i];
        dstP2[delta2[b] + i] = pay[i];
    }
}

// deg_in partials: block (db, g) histograms dst_local over row cells.
__global__ void degin2_kernel(const unsigned* __restrict__ dstP2, const unsigned* __restrict__ curC,
                              unsigned CAP2, unsigned short* __restrict__ pDegIn, int NSB, int GS) {
    __shared__ unsigned h[BNODES];
    {
        uint4v* hv = (uint4v*)h;
        for (int t = threadIdx.x; t < BNODES / 4; t += DTB) hv[t] = (uint4v)0u;
    }
    __syncthreads();
    int db = blockIdx.x / GNUM, g = blockIdx.x % GNUM;
    int sbEnd = (g + 1) * GS; if (sbEnd > NSB) sbEnd = NSB;
    for (int sb = g * GS; sb < sbEnd; ++sb) {
        unsigned cell = (unsigned)(db * NSB + sb);
        unsigned lo = cell * CAP2;
        unsigned hi = curC[cell * CSTR];
        unsigned i1 = hi & ~3u;
        const uint4v* qp = (const uint4v*)(dstP2 + lo);
        for (unsigned q = threadIdx.x; q < (i1 - lo) / 4u; q += DTB) {
            uint4v e4 = qp[q];
            atomicAdd(&h[e4.x >> BSH2], 1u);
            atomicAdd(&h[e4.y >> BSH2], 1u);
            atomicAdd(&h[e4.z >> BSH2], 1u);
            atomicAdd(&h[e4.w >> BSH2], 1u);
        }
        if (threadIdx.x < hi - i1)
            atomicAdd(&h[dstP2[i1 + threadIdx.x] >> BSH2], 1u);
    }
    __syncthreads();
    unsigned short* row = pDegIn + (size_t)blockIdx.x * BNODES;
    for (int t = threadIdx.x; t < BNODES; t += DTB) row[t] = (unsigned short)h[t];
}

// deg_out partials: block (sb, g) histograms src_local over column cells.
// R14b FIX: NB passed and dbEnd clamped (unclamped tail group was an OOB
// curC read -> (i1-lo) underflow -> GPU hang).
__global__ void degout2_kernel(const unsigned* __restrict__ dstP2, const unsigned* __restrict__ curC,
                               unsigned CAP2, unsigned short* __restrict__ pDegOut,
                               int NSB, int NB, int GS) {
    __shared__ unsigned h[SNODES];
    {
        uint4v* hv = (uint4v*)h;
        for (int t = threadIdx.x; t < SNODES / 4; t += DTB) hv[t] = (uint4v)0u;
    }
    __syncthreads();
    int sb = blockIdx.x / GOUT, g = blockIdx.x % GOUT;
    int dbEnd = (g + 1) * GS; if (dbEnd > NB) dbEnd = NB;
    for (int db = g * GS; db < dbEnd; ++db) {
        unsigned cell = (unsigned)(db * NSB + sb);
        unsigned lo = cell * CAP2;
        unsigned hi = curC[cell * CSTR];
        unsigned i1 = hi & ~3u;
        const uint4v* qp = (const uint4v*)(dstP2 + lo);
        for (unsigned q = threadIdx.x; q < (i1 - lo) / 4u; q += DTB) {
            uint4v e4 = qp[q];
            atomicAdd(&h[e4.x & (SNODES - 1)], 1u);
            atomicAdd(&h[e4.y & (SNODES - 1)], 1u);
            atomicAdd(&h[e4.z & (SNODES - 1)], 1u);
            atomicAdd(&h[e4.w & (SNODES - 1)], 1u);
        }
        if (threadIdx.x < hi - i1)
            atomicAdd(&h[dstP2[i1 + threadIdx.x] & (SNODES - 1)], 1u);
    }
    __syncthreads();
    unsigned short* row = pDegOut + (size_t)blockIdx.x * SNODES;
    for (int t = threadIdx.x; t < SNODES; t += DTB) row[t] = (unsigned short)h[t];
}

__global__ void prep2_kernel(const unsigned short* __restrict__ pDegIn,
                             const unsigned short* __restrict__ pDegOut,
                             float* __restrict__ pio, float* __restrict__ h0s,
                             float* __restrict__ isiA, int NSB, int N, int Npad) {
    int i = blockIdx.x * TB + threadIdx.x;
    if (i >= Npad) return;
    int db = i >> BSH, l13 = i & (BNODES - 1);
    unsigned din_u = 0, dout_u = 0;
    for (int g = 0; g < GNUM; ++g)
        din_u += pDegIn[(size_t)(db * GNUM + g) * BNODES + l13];
    if (i < N) {
        int sb = i >> BSH2, l12 = i & (SNODES - 1);
        for (int g = 0; g < GOUT; ++g)
            dout_u += pDegOut[(size_t)(sb * GOUT + g) * SNODES + l12];
    }
    float din = (float)din_u, dout = (float)dout_u;
    float a  = 1.0f / sqrtf(fmaxf(din, 1.0f));
    float bo = 1.0f / sqrtf(fmaxf(dout, 1.0f));
    pio[i]  = a * bo;
    h0s[i]  = din * bo;    // pad nodes: din=0 -> 0
    isiA[i] = a;
}

// 2D weighted histogram, LDS slice gather: h (32KB) + slice (16KB) = 48KB
// -> 3 blocks/CU. Random access through LDS banks, not the TA.
template <int LAST>
__global__ void wh2s_kernel(const unsigned* __restrict__ dstP2, const unsigned* __restrict__ curC,
                            unsigned CAP2, const float* __restrict__ table,
                            float* __restrict__ pOut, int NSB, int GS) {
    __shared__ float h[BNODES];
    __shared__ float slice[SNODES];
    {
        float4v* hv = (float4v*)h;
        for (int t = threadIdx.x; t < BNODES / 4; t += DTB) hv[t] = (float4v)0.0f;
    }
    int db = blockIdx.x / GNUM, g = blockIdx.x % GNUM;
    int sbEnd = (g + 1) * GS; if (sbEnd > NSB) sbEnd = NSB;
    for (int sb = g * GS; sb < sbEnd; ++sb) {
        __syncthreads();   // prior iter's slice readers done (covers h zero too)
        {
            const float4v* tp = (const float4v*)(table + ((size_t)sb << BSH2));
            float4v* sp = (float4v*)slice;
            for (int t = threadIdx.x; t < SNODES / 4; t += DTB) sp[t] = tp[t];
        }
        __syncthreads();
        unsigned cell = (unsigned)(db * NSB + sb);
        unsigned lo = cell * CAP2;       // CAP2 128-aligned -> 16B-aligned base
        unsigned hi = curC[cell * CSTR];
        unsigned i1 = hi & ~3u;
        const uint4v* qp = (const uint4v*)(dstP2 + lo);
        for (unsigned q = threadIdx.x; q < (i1 - lo) / 4u; q += DTB) {
            uint4v e4 = LAST ? __builtin_nontemporal_load(qp + q) : qp[q];
            float t0 = slice[e4.x & (SNODES - 1)];
            float t1 = slice[e4.y & (SNODES - 1)];
            float t2 = slice[e4.z & (SNODES - 1)];
            float t3 = slice[e4.w & (SNODES - 1)];
            atomicAdd(&h[e4.x >> BSH2], t0);
            atomicAdd(&h[e4.y >> BSH2], t1);
            atomicAdd(&h[e4.z >> BSH2], t2);
            atomicAdd(&h[e4.w >> BSH2], t3);
        }
        if (threadIdx.x < hi - i1) {
            unsigned e = dstP2[i1 + threadIdx.x];
            atomicAdd(&h[e >> BSH2], slice[e & (SNODES - 1)]);
        }
    }
    __syncthreads();
    float4v* rowv = (float4v*)(pOut + (size_t)blockIdx.x * BNODES);
    float4v* hv = (float4v*)h;
    for (int t = threadIdx.x; t < BNODES / 4; t += DTB) rowv[t] = hv[t];
}

// ---------------- 1D fallback kernels (R11 path) ----------------

__global__ void deghist_kernel(const unsigned short* __restrict__ srcP, const unsigned* __restrict__ dstP,
                               const unsigned* __restrict__ curS, const unsigned* __restrict__ curD,
                               unsigned CAP, unsigned* __restrict__ pDeg, int Jlg) {
    __shared__ unsigned h[BNODES];
    {
        uint4v* hv = (uint4v*)h;
        for (int t = threadIdx.x; t < BNODES / 4; t += DTB) hv[t] = (uint4v)0u;
    }
    __syncthreads();
    int b = blockIdx.x >> Jlg;
    int j = blockIdx.x & ((1 << Jlg) - 1);
    unsigned s0 = (unsigned)b * CAP;
    {
        unsigned cD = curD[b * CSTR] - s0;
        unsigned lo = (unsigned)(((unsigned long long)cD * (unsigned)j) >> Jlg);
        unsigned hi = (unsigned)(((unsigned long long)cD * (unsigned)(j + 1)) >> Jlg);
        for (unsigned i = lo + threadIdx.x; i < hi; i += DTB)
            atomicAdd(&h[dstP[s0 + i] >> 19], 0x10000u);
    }
    {
        unsigned cS = curS[b * CSTR] - s0;
        unsigned lo = (unsigned)(((unsigned long long)cS * (unsigned)j) >> Jlg);
        unsigned hi = (unsigned)(((unsigned long long)cS * (unsigned)(j + 1)) >> Jlg);
        for (unsigned i = lo + threadIdx.x; i < hi; i += DTB)
            atomicAdd(&h[__builtin_nontemporal_load(&srcP[s0 + i])], 1u);
    }
    __syncthreads();
    uint4v* rowv = (uint4v*)(pDeg + (size_t)blockIdx.x * BNODES);
    uint4v* hv = (uint4v*)h;
    for (int t = threadIdx.x; t < BNODES / 4; t += DTB) rowv[t] = hv[t];
}

__global__ void prep_kernel(const unsigned* __restrict__ pDeg,
                            float* __restrict__ pio, float* __restrict__ h0s,
                            float* __restrict__ isiA, int Jlg, int Npad) {
    int i = blockIdx.x * TB + threadIdx.x;
    if (i >= Npad) return;
    int b = i >> BSH, l = i & (BNODES - 1);
    int J = 1 << Jlg;
    unsigned din_u = 0, dout_u = 0;
    for (int j = 0; j < J; ++j) {
        unsigned v = __builtin_nontemporal_load(&pDeg[(size_t)((b << Jlg) + j) * BNODES + l]);
        din_u += v >> 16; dout_u += v & 0xFFFFu;
    }
    float din = (float)din_u, dout = (float)dout_u;
    float a  = 1.0f / sqrtf(fmaxf(din, 1.0f));
    float bo = 1.0f / sqrtf(fmaxf(dout, 1.0f));
    pio[i]  = a * bo;
    h0s[i]  = din * bo;
    isiA[i] = a;
}

template <int LAST>
__global__ void wh_kernel(const unsigned* __restrict__ dstP, const unsigned* __restrict__ curD,
                          unsigned CAP, const float* __restrict__ table,
                          float* __restrict__ pOut, int Jlg) {
    __shared__ float h[BNODES];
    {
        float4v* hv = (float4v*)h;
        for (int t = threadIdx.x; t < BNODES / 4; t += DTB) hv[t] = (float4v)0.0f;
    }
    __syncthreads();
    int b = blockIdx.x >> Jlg;
    int j = blockIdx.x & ((1 << Jlg) - 1);
    unsigned s0 = (unsigned)b * CAP;
    unsigned cD = curD[b * CSTR] - s0;
    unsigned lo = (unsigned)(((unsigned long long)cD * (unsigned)j) >> Jlg);
    unsigned hi = (unsigned)(((unsigned long long)cD * (unsigned)(j + 1)) >> Jlg);
    unsigned i0 = (lo + 3u) & ~3u;
    unsigned i1 = hi & ~3u;
    if (i0 >= i1) {
        for (unsigned i = lo + threadIdx.x; i < hi; i += DTB) {
            unsigned e = dstP[s0 + i];
            atomicAdd(&h[e >> 19], table[e & 0x7FFFFu]);
        }
    } else {
        if (threadIdx.x < i0 - lo) {
            unsigned e = dstP[s0 + lo + threadIdx.x];
            atomicAdd(&h[e >> 19], table[e & 0x7FFFFu]);
        }
        const uint4v* qp = (const uint4v*)(dstP + s0);
        for (unsigned q = i0 / 4u + threadIdx.x; q < i1 / 4u; q += DTB) {
            uint4v e4 = LAST ? __builtin_nontemporal_load(qp + q) : qp[q];
            float t0 = table[e4.x & 0x7FFFFu];
            float t1 = table[e4.y & 0x7FFFFu];
            float t2 = table[e4.z & 0x7FFFFu];
            float t3 = table[e4.w & 0x7FFFFu];
            atomicAdd(&h[e4.x >> 19], t0);
            atomicAdd(&h[e4.y >> 19], t1);
            atomicAdd(&h[e4.z >> 19], t2);
            atomicAdd(&h[e4.w >> 19], t3);
        }
        if (threadIdx.x < hi - i1) {
            unsigned e = dstP[s0 + i1 + threadIdx.x];
            atomicAdd(&h[e >> 19], table[e & 0x7FFFFu]);
        }
    }
    __syncthreads();
    float4v* rowv = (float4v*)(pOut + (size_t)blockIdx.x * BNODES);
    float4v* hv = (float4v*)h;
    for (int t = threadIdx.x; t < BNODES / 4; t += DTB) rowv[t] = hv[t];
}

// ---------------- shared tail kernels (J = partial count, runtime) ----------------

__global__ void mid_kernel(const float* __restrict__ pC, const float* __restrict__ pio,
                           float* __restrict__ sarr, int J, int Npad) {
    int i = blockIdx.x * TB + threadIdx.x;
    if (i >= Npad) return;
    int b = i >> BSH, l = i & (BNODES - 1);
    float t1 = 0.0f;
    for (int j = 0; j < J; ++j)
        t1 += __builtin_nontemporal_load(&pC[(size_t)(b * J + j) * BNODES + l]);
    sarr[i] = t1 * pio[i];
}

__global__ void poolfinal_kernel(const float* __restrict__ pT, const float* __restrict__ isiA,
                                 const int* __restrict__ graph_ids,
                                 float* __restrict__ Xsum, int J, int N) {
    int i = blockIdx.x * TB + threadIdx.x;
    bool valid = i < N;
    int ii = valid ? i : (N - 1);
    int b = ii >> BSH, l = ii & (BNODES - 1);
    float t2 = 0.0f;
    for (int j = 0; j < J; ++j)
        t2 += __builtin_nontemporal_load(&pT[(size_t)(b * J + j) * BNODES + l]);
    float x = valid ? t2 * isiA[ii] : 0.0f;
    int g = graph_ids[ii];
    int g0 = __shfl(g, 0, 64);
    bool uniform = __all((!valid) || (g == g0));
    if (uniform) {
#pragma unroll
        for (int off = 32; off >= 1; off >>= 1) x += __shfl_down(x, off, 64);
        if ((threadIdx.x & 63) == 0) atomicAdd(&Xsum[g0], x);
    } else if (valid) {
        atomicAdd(&Xsum[g], x);
    }
}

__global__ void final_kernel(const float* __restrict__ Xsum, const int* __restrict__ graph_ids,
                             const float* __restrict__ W1, const float* __restrict__ W2,
                             const float* __restrict__ Wlast,
                             float* __restrict__ out, int N, int GC) {
    int i = blockIdx.x * TB + threadIdx.x;
    if (i < GC) {
        int g = i >> 3, j = i & 7;
        int lo = 0, hi = N;
        while (lo < hi) { int m = (lo + hi) >> 1; if (graph_ids[m] < g) lo = m + 1; else hi = m; }
        int lo2 = lo, hi2 = N;
        while (lo2 < hi2) { int m = (lo2 + hi2) >> 1; if (graph_ids[m] < g + 1) lo2 = m + 1; else hi2 = m; }
        float c = (float)(lo2 - lo);
        float r = 0.0f;
#pragma unroll
        for (int cc = 0; cc < 8; ++cc) {
            float m = 0.0f;
#pragma unroll
            for (int k = 0; k < 8; ++k) m += fmaxf(W1[k], 0.0f) * W2[k * 8 + cc];
            r += fmaxf(m, 0.0f) * Wlast[cc * 8 + j];
        }
        out[i] = Xsum[g] / fmaxf(c, 1.0f) * r;
    }
}

// ---------------- fallback (atomic) path ----------------

__global__ void fb_deg_kernel(const int* __restrict__ src, const int* __restrict__ dst,
                              float* __restrict__ deg_out, float* __restrict__ deg_in, int E) {
    int i = blockIdx.x * TB + threadIdx.x;
    if (i < E) {
        atomicAdd(&deg_out[src[i]], 1.0f);
        atomicAdd(&deg_in[dst[i]], 1.0f);
    }
}

__global__ void fb_prep_kernel(const float* __restrict__ deg_in, const float* __restrict__ deg_out,
                               float* __restrict__ isi, float* __restrict__ iso,
                               float* __restrict__ h0s, int N) {
    int i = blockIdx.x * TB + threadIdx.x;
    if (i < N) {
        float di = deg_in[i], dn = deg_out[i];
        float a = 1.0f / sqrtf(fmaxf(di, 1.0f));
        float b = 1.0f / sqrtf(fmaxf(dn, 1.0f));
        isi[i] = a; iso[i] = b; h0s[i] = di * b;
    }
}

__global__ void fb_conv_kernel(const int* __restrict__ src, const int* __restrict__ dst,
                               const float* __restrict__ vals, float* __restrict__ t, int E) {
    int i = blockIdx.x * TB + threadIdx.x;
    if (i < E) atomicAdd(&t[dst[i]], vals[src[i]]);
}

__global__ void fb_mid_kernel(const float* __restrict__ agg1, const float* __restrict__ isi,
                              const float* __restrict__ iso, float* __restrict__ s, int N) {
    int i = blockIdx.x * TB + threadIdx.x;
    if (i < N) s[i] = agg1[i] * isi[i] * iso[i];
}

__global__ void fb_pool_kernel(const float* __restrict__ t2, const float* __restrict__ isi,
                               const int* __restrict__ graph_ids,
                               float* __restrict__ Xsum, float* __restrict__ counts, int N) {
    int i = blockIdx.x * TB + threadIdx.x;
    bool valid = i < N;
    int ii = valid ? i : (N - 1);
    float x = valid ? t2[ii] * isi[ii] : 0.0f;
    float cnt = valid ? 1.0f : 0.0f;
    int g = graph_ids[ii];
    int g0 = __shfl(g, 0, 64);
    bool uniform = __all((!valid) || (g == g0));
    if (uniform) {
#pragma unroll
        for (int off = 32; off >= 1; off >>= 1) {
            x += __shfl_down(x, off, 64);
            cnt += __shfl_down(cnt, off, 64);
        }
        if ((threadIdx.x & 63) == 0) { atomicAdd(&Xsum[g0], x); atomicAdd(&counts[g0], cnt); }
    } else if (valid) {
        atomicAdd(&Xsum[g], x); atomicAdd(&counts[g], 1.0f);
    }
}

__global__ void fb_final_kernel(const float* __restrict__ Xsum, const float* __restrict__ counts,
                                const float* __restrict__ W1, const float* __restrict__ W2,
                                const float* __restrict__ Wlast, float* __restrict__ out, int GC) {
    int i = blockIdx.x * TB + threadIdx.x;
    if (i < GC) {
        int g = i >> 3, j = i & 7;
        float r = 0.0f;
#pragma unroll
        for (int c = 0; c < 8; ++c) {
            float m = 0.0f;
#pragma unroll
            for (int k = 0; k < 8; ++k) m += fmaxf(W1[k], 0.0f) * W2[k * 8 + c];
            r += fmaxf(m, 0.0f) * Wlast[c * 8 + j];
        }
        out[i] = Xsum[g] / fmaxf(counts[g], 1.0f) * r;
    }
}

// ---------------- launch ----------------

extern "C" void kernel_launch(void* const* d_in, const int* in_sizes, int n_in,
                              void* d_out, int out_size, void* d_ws, size_t ws_size,
                              hipStream_t stream) {
    const float* W1        = (const float*)d_in[0];
    const float* W2        = (const float*)d_in[1];
    const float* Wlast     = (const float*)d_in[2];
    const int*   src       = (const int*)d_in[3];
    const int*   dst       = (const int*)d_in[4];
    const int*   graph_ids = (const int*)d_in[5];
    float* out = (float*)d_out;

    const int E = in_sizes[3];
    const int N = in_sizes[5];
    const int G = out_size / 8;

    int NB   = (N + BNODES - 1) >> BSH;
    int Npad = NB << BSH;
    int NCH  = (E + SCH - 1) / SCH;
    unsigned CAP = (unsigned)(((E / (NB > 0 ? NB : 1)) + 8192 + 511) & ~511);
    char* bp = (char*)d_ws;

    // ---- 2D layout (preferred) ----
    bool fast2D = false;
    size_t q_reg1 = 0, q_dstP2 = 0, q_curD = 0, q_curC = 0, q_pio = 0, q_h0sar = 0,
           q_isi = 0, q_Xsum = 0;
    size_t degInBytes = 0;
    int NSB = (N + SNODES - 1) >> BSH2;
    int cells = NB * NSB;
    unsigned CAP2 = 0;
    int GS_sb = (NSB + GNUM - 1) / GNUM;
    int GS_db = (NB + GOUT - 1) / GOUT;
    if (N <= (1 << 19) && NB <= MAXNB && NSB <= MAXSB && E >= 1) {
        CAP2 = (unsigned)(((E / (cells > 0 ? cells : 1)) + 384 + 127) & ~127);
        degInBytes = (size_t)NB * GNUM * BNODES * 2;
        size_t degOutBytes = (size_t)NSB * GOUT * SNODES * 2;
        size_t pCBytes = (size_t)NB * GNUM * BNODES * 4;
        size_t dstPBytes = (size_t)NB * CAP * 4;
        size_t reg1 = dstPBytes;
        if (degInBytes + degOutBytes > reg1) reg1 = degInBytes + degOutBytes;
        if (pCBytes > reg1) reg1 = pCBytes;
        size_t off = 0;
        auto A = [&](size_t bytes) { size_t o = off; off = (off + bytes + 127) & ~(size_t)127; return o; };
        q_reg1  = A(reg1);
        q_dstP2 = A((size_t)cells * CAP2 * 4 + (size_t)CAP2 * 4);   // + slack row
        q_curD  = A((size_t)NB * CSTR * 4);
        q_curC  = A((size_t)cells * CSTR * 4);
        q_pio   = A((size_t)Npad * 4);
        q_h0sar = A((size_t)Npad * 4);
        q_isi   = A((size_t)Npad * 4);
        q_Xsum  = A((size_t)G * 4);
        fast2D = (off <= ws_size);
    }

    if (fast2D) {
        unsigned* dstP  = (unsigned*)(bp + q_reg1);
        unsigned* dstP2 = (unsigned*)(bp + q_dstP2);
        unsigned* curD  = (unsigned*)(bp + q_curD);
        unsigned* curC  = (unsigned*)(bp + q_curC);
        unsigned short* pDegIn  = (unsigned short*)(bp + q_reg1);
        unsigned short* pDegOut = (unsigned short*)(bp + q_reg1 + degInBytes);
        float* pC   = (float*)(bp + q_reg1);
        float* pT   = (float*)(bp + q_reg1);
        float* pio  = (float*)(bp + q_pio);
        float* h0s  = (float*)(bp + q_h0sar);
        float* sarr = (float*)(bp + q_h0sar);
        float* isiA = (float*)(bp + q_isi);
        float* Xsum = (float*)(bp + q_Xsum);

        int gridNp = (Npad + TB - 1) / TB;
        int gridN  = (N + TB - 1) / TB;
        int mx = cells > G ? cells : G; if (NB > mx) mx = NB;
        int gridI  = (mx + TB - 1) / TB;
        int MAXCH  = (int)((CAP + SCH2 - 1) / SCH2);
        int NCH1 = (NCH + 1) / 2;
        int NCH2 = NCH - NCH1;

        init_kernel<<<gridI, TB, 0, stream>>>(curD, nullptr, curC, Xsum, NB, CAP, cells, CAP2, G);
        scatter_sort_kernel<<<NCH1, STB, 0, stream>>>(src, dst, curD, nullptr, dstP, nullptr, NB, E, 0);
        if (NCH2 > 0)
            scatter_sort_kernel<<<NCH2, STB, 0, stream>>>(src, dst, curD, nullptr, dstP, nullptr, NB, E, NCH1);
        subsort_kernel<<<NB * MAXCH, STB, 0, stream>>>(dstP, curD, curC, dstP2, CAP, CAP2, NSB, MAXCH);
        degin2_kernel<<<NB * GNUM, DTB, 0, stream>>>(dstP2, curC, CAP2, pDegIn, NSB, GS_sb);
        degout2_kernel<<<NSB * GOUT, DTB, 0, stream>>>(dstP2, curC, CAP2, pDegOut, NSB, NB, GS_db);
        prep2_kernel<<<gridNp, TB, 0, stream>>>(pDegIn, pDegOut, pio, h0s, isiA, NSB, N, Npad);
        wh2s_kernel<0><<<NB * GNUM, DTB, 0, stream>>>(dstP2, curC, CAP2, h0s, pC, NSB, GS_sb);
        mid_kernel<<<gridNp, TB, 0, stream>>>(pC, pio, sarr, GNUM, Npad);
        wh2s_kernel<1><<<NB * GNUM, DTB, 0, stream>>>(dstP2, curC, CAP2, sarr, pT, NSB, GS_sb);
        poolfinal_kernel<<<gridN, TB, 0, stream>>>(pT, isiA, graph_ids, Xsum, GNUM, N);
        final_kernel<<<(out_size + TB - 1) / TB, TB, 0, stream>>>(Xsum, graph_ids,
                                                                  W1, W2, Wlast, out, N, out_size);
        return;
    }

    // ---- 1D layout (R11 fallback) ----
    int Jlg = 4;
    size_t req = 0;
    size_t o_dstP, o_srcP, o_curD, o_curS, o_part, o_pio, o_h0sar, o_isi, o_Xsum;
    for (;; --Jlg) {
        int J = 1 << Jlg;
        size_t off = 0;
        auto A = [&](size_t bytes) { size_t o = off; off = (off + bytes + 127) & ~(size_t)127; return o; };
        o_dstP  = A((size_t)NB * CAP * 4);
        o_srcP  = A((size_t)NB * CAP * 2);
        o_curD  = A((size_t)NB * CSTR * 4);
        o_curS  = A((size_t)NB * CSTR * 4);
        o_part  = A((size_t)NB * J * BNODES * 4);
        o_pio   = A((size_t)Npad * 4);
        o_h0sar = A((size_t)Npad * 4);
        o_isi   = A((size_t)Npad * 4);
        o_Xsum  = A((size_t)G * 4);
        req = off;
        if (req <= ws_size || Jlg == 0) break;
    }

    bool fast = (N <= (1 << 19)) && (NB <= MAXNB) && (ws_size >= req) && (E >= 1);

    if (fast) {
        unsigned*       dstP = (unsigned*)(bp + o_dstP);
        unsigned short* srcP = (unsigned short*)(bp + o_srcP);
        unsigned* curD = (unsigned*)(bp + o_curD);
        unsigned* curS = (unsigned*)(bp + o_curS);
        unsigned* pDeg = (unsigned*)(bp + o_part);
        float*    pC   = (float*)(bp + o_part);
        float*    pT   = (float*)(bp + o_part);
        float* pio  = (float*)(bp + o_pio);
        float* h0s  = (float*)(bp + o_h0sar);
        float* sarr = (float*)(bp + o_h0sar);
        float* isiA = (float*)(bp + o_isi);
        float* Xsum = (float*)(bp + o_Xsum);

        int gridNp = (Npad + TB - 1) / TB;
        int gridN  = (N + TB - 1) / TB;
        int J = 1 << Jlg;
        int gridI = ((NB > G ? NB : G) + TB - 1) / TB;
        int NCH1 = (NCH + 1) / 2;
        int NCH2 = NCH - NCH1;

        init_kernel<<<gridI, TB, 0, stream>>>(curD, curS, nullptr, Xsum, NB, CAP, 0, 0, G);
        scatter_sort_kernel<<<NCH1, STB, 0, stream>>>(src, dst, curD, curS, dstP, srcP, NB, E, 0);
        if (NCH2 > 0)
            scatter_sort_kernel<<<NCH2, STB, 0, stream>>>(src, dst, curD, curS, dstP, srcP, NB, E, NCH1);
        deghist_kernel<<<NB * J, DTB, 0, stream>>>(srcP, dstP, curS, curD, CAP, pDeg, Jlg);
        prep_kernel<<<gridNp, TB, 0, stream>>>(pDeg, pio, h0s, isiA, Jlg, Npad);
        wh_kernel<0><<<NB * J, DTB, 0, stream>>>(dstP, curD, CAP, h0s, pC, Jlg);
        mid_kernel<<<gridNp, TB, 0, stream>>>(pC, pio, sarr, J, Npad);
        wh_kernel<1><<<NB * J, DTB, 0, stream>>>(dstP, curD, CAP, sarr, pT, Jlg);
        poolfinal_kernel<<<gridN, TB, 0, stream>>>(pT, isiA, graph_ids, Xsum, J, N);
        final_kernel<<<(out_size + TB - 1) / TB, TB, 0, stream>>>(Xsum, graph_ids,
                                                                  W1, W2, Wlast, out, N, out_size);
    } else {
        float* ws = (float*)d_ws;
        size_t f = 0;
        auto FA = [&](size_t n) { size_t o = f; f += (n + 3) & ~(size_t)3; return o; };
        size_t f_degin  = FA(N);
        size_t f_degout = FA(N);
        size_t f_agg1   = FA(N);
        size_t f_t2     = FA(N);
        size_t f_Xsum   = FA(G);
        size_t f_cnt    = FA(G);
        size_t zf = f;
        size_t f_isi = FA(N);
        size_t f_iso = FA(N);
        size_t f_h0s = FA(N);
        size_t f_s   = FA(N);
        hipMemsetAsync(ws, 0, zf * sizeof(float), stream);
        int gridE = (E + TB - 1) / TB;
        int gridN = (N + TB - 1) / TB;
        int gridO = (out_size + TB - 1) / TB;
        fb_deg_kernel<<<gridE, TB, 0, stream>>>(src, dst, ws + f_degout, ws + f_degin, E);
        fb_prep_kernel<<<gridN, TB, 0, stream>>>(ws + f_degin, ws + f_degout,
                                                 ws + f_isi, ws + f_iso, ws + f_h0s, N);
        fb_conv_kernel<<<gridE, TB, 0, stream>>>(src, dst, ws + f_h0s, ws + f_agg1, E);
        fb_mid_kernel<<<gridN, TB, 0, stream>>>(ws + f_agg1, ws + f_isi, ws + f_iso, ws + f_s, N);
        fb_conv_kernel<<<gridE, TB, 0, stream>>>(src, dst, ws + f_s, ws + f_t2, E);
        fb_pool_kernel<<<gridN, TB, 0, stream>>>(ws + f_t2, ws + f_isi, graph_ids,
                                                 ws + f_Xsum, ws + f_cnt, N);
        fb_final_kernel<<<gridO, TB, 0, stream>>>(ws + f_Xsum, ws + f_cnt, W1, W2, Wlast,
                                                  out, out_size);
    }
}

// Round 10
// 369.527 us; speedup vs baseline: 1.1469x; 1.1469x over previous
//
#include <hip/hip_runtime.h>

// GCN rank-1 collapse + one-pass counting-sort bucket partition (R15 = R11
// reverted, final). R12-R14 post-mortem: the weighted-histogram gather pass
// is pinned at 61-73us across FOUR implementations (random-L2 gather 61,
// LDS-staged 34%-occ 73, L1-resident 62.5, LDS-staged 45%-occ 73). The
// invariant is the per-edge random-access step (10M gathers + 10M LDS
// atomics per pass), not cache level, MLP, or banks. R11's 1D version is
// the cheapest; reverting to it. Structure: 62-bucket dual partition
// (dstP u32 payload, srcP u16), packed deghist, 2x wh passes (J=16,
// DTB=512, 4-wide ILP), rank-1 collapsed MLP in final_kernel.

#define TB 256
#define DTB 512
#define STB 512
#define BSH 13
#define BNODES 8192
#define MAXNB 64
#define SCH 4096
#define SCH4 (SCH / 4)
#define EPT 8
#define CSTR 16
#define INVB 0xFFFFFFFFu

typedef __attribute__((ext_vector_type(4))) int int4v;
typedef __attribute__((ext_vector_type(4))) unsigned uint4v;
typedef __attribute__((ext_vector_type(2))) unsigned uint2v;
typedef __attribute__((ext_vector_type(4))) float float4v;

__global__ void init_kernel(unsigned* __restrict__ curD, unsigned* __restrict__ curS,
                            float* __restrict__ Xsum, int NB, unsigned CAP, int G) {
    int i = blockIdx.x * TB + threadIdx.x;
    if (i < NB) { curD[i * CSTR] = (unsigned)i * CAP; curS[i * CSTR] = (unsigned)i * CAP; }
    if (i < G) Xsum[i] = 0.0f;
}

__global__ void scatter_sort_kernel(const int* __restrict__ src, const int* __restrict__ dst,
                                    unsigned* __restrict__ curD, unsigned* __restrict__ curS,
                                    unsigned* __restrict__ dstP, unsigned short* __restrict__ srcP,
                                    int NB, int E, int blk0) {
    __shared__ unsigned cntD[MAXNB], cntS[MAXNB];     // counts -> insert cursors
    __shared__ unsigned deltaD[MAXNB], deltaS[MAXNB]; // globalBase - localExclusive
    __shared__ unsigned totD_s, totS_s;
    __shared__ unsigned payD[SCH];
    __shared__ unsigned short valS[SCH];
    __shared__ unsigned char mapD[SCH], mapS[SCH];

    int tid = threadIdx.x;
    if (tid < MAXNB) { cntD[tid] = 0u; cntS[tid] = 0u; }
    __syncthreads();

    unsigned sA[EPT], dA[EPT], bD[EPT], bS[EPT];
    int blk = blockIdx.x + blk0;
#pragma unroll
    for (int v = 0; v < 2; ++v) {
        int q = blk * SCH4 + v * STB + tid;
        int be = q * 4;
        if (be + 3 < E) {
            int4v s4 = __builtin_nontemporal_load((const int4v*)src + q);
            int4v d4 = __builtin_nontemporal_load((const int4v*)dst + q);
#pragma unroll
            for (int k = 0; k < 4; ++k) {
                sA[v*4+k] = (unsigned)s4[k];
                dA[v*4+k] = (unsigned)d4[k];
                bD[v*4+k] = dA[v*4+k] >> BSH;
                bS[v*4+k] = sA[v*4+k] >> BSH;
            }
        } else {
#pragma unroll
            for (int k = 0; k < 4; ++k) {
                int j = be + k;
                if (j < E) {
                    sA[v*4+k] = (unsigned)src[j];
                    dA[v*4+k] = (unsigned)dst[j];
                    bD[v*4+k] = dA[v*4+k] >> BSH;
                    bS[v*4+k] = sA[v*4+k] >> BSH;
                } else {
                    bD[v*4+k] = INVB; bS[v*4+k] = INVB;
                    sA[v*4+k] = 0u; dA[v*4+k] = 0u;
                }
            }
        }
    }

#pragma unroll
    for (int k = 0; k < EPT; ++k) {
        if (bD[k] != INVB) {
            atomicAdd(&cntD[bD[k]], 1u);
            atomicAdd(&cntS[bS[k]], 1u);
        }
    }
    __syncthreads();

    int wv = tid >> 6, ln = tid & 63;
    if (wv == 0) {
        unsigned x = (ln < NB) ? cntD[ln] : 0u;
        unsigned inc = x;
#pragma unroll
        for (int o = 1; o < 64; o <<= 1) {
            unsigned y = __shfl_up(inc, o, 64);
            if (ln >= o) inc += y;
        }
        unsigned exc = inc - x;
        if (ln < NB) {
            unsigned gb = atomicAdd(&curD[ln * CSTR], x);   // exact reservation, 1 line/bucket
            deltaD[ln] = gb - exc;
            cntD[ln] = exc;                                 // insert cursor
        }
        if (ln == 63) totD_s = inc;
    } else if (wv == 1) {
        unsigned x = (ln < NB) ? cntS[ln] : 0u;
        unsigned inc = x;
#pragma unroll
        for (int o = 1; o < 64; o <<= 1) {
            unsigned y = __shfl_up(inc, o, 64);
            if (ln >= o) inc += y;
        }
        unsigned exc = inc - x;
        if (ln < NB) {
            unsigned gb = atomicAdd(&curS[ln * CSTR], x);
            deltaS[ln] = gb - exc;
            cntS[ln] = exc;
        }
        if (ln == 63) totS_s = inc;
    }
    __syncthreads();

#pragma unroll
    for (int k = 0; k < EPT; ++k) {
        if (bD[k] != INVB) {
            unsigned p = atomicAdd(&cntD[bD[k]], 1u);
            payD[p] = ((dA[k] & (BNODES - 1)) << 19) | sA[k];
            mapD[p] = (unsigned char)bD[k];
            unsigned p2 = atomicAdd(&cntS[bS[k]], 1u);
            valS[p2] = (unsigned short)(sA[k] & (BNODES - 1));
            mapS[p2] = (unsigned char)bS[k];
        }
    }
    __syncthreads();

    unsigned tD = totD_s, tS = totS_s;
    for (unsigned i = tid; i < tD; i += STB) {
        unsigned b = mapD[i];
        dstP[deltaD[b] + i] = payD[i];   // delta[b]+i = gBase + (i - exc[b])
    }
    for (unsigned i = tid; i < tS; i += STB) {
        unsigned b = mapS[i];
        srcP[deltaS[b] + i] = valS[i];
    }
}

// Packed degrees per sub-block: high16 = deg_in (dstP), low16 = deg_out (srcP).
__global__ void deghist_kernel(const unsigned short* __restrict__ srcP, const unsigned* __restrict__ dstP,
                               const unsigned* __restrict__ curS, const unsigned* __restrict__ curD,
                               unsigned CAP, unsigned* __restrict__ pDeg, int Jlg) {
    __shared__ unsigned h[BNODES];
    {
        uint4v* hv = (uint4v*)h;
        for (int t = threadIdx.x; t < BNODES / 4; t += DTB) hv[t] = (uint4v)0u;
    }
    __syncthreads();
    int b = blockIdx.x >> Jlg;
    int j = blockIdx.x & ((1 << Jlg) - 1);
    unsigned s0 = (unsigned)b * CAP;

    // deg_in from dstP (4-wide ILP)
    {
        unsigned cD = curD[b * CSTR] - s0;
        unsigned lo = (unsigned)(((unsigned long long)cD * (unsigned)j) >> Jlg);
        unsigned hi = (unsigned)(((unsigned long long)cD * (unsigned)(j + 1)) >> Jlg);
        unsigned i0 = (lo + 3u) & ~3u;
        unsigned i1 = hi & ~3u;
        if (i0 >= i1) {
            for (unsigned i = lo + threadIdx.x; i < hi; i += DTB)
                atomicAdd(&h[dstP[s0 + i] >> 19], 0x10000u);
        } else {
            if (threadIdx.x < i0 - lo)
                atomicAdd(&h[dstP[s0 + lo + threadIdx.x] >> 19], 0x10000u);
            const uint4v* qp = (const uint4v*)(dstP + s0);
            for (unsigned q = i0 / 4u + threadIdx.x; q < i1 / 4u; q += DTB) {
                uint4v e4 = qp[q];
                atomicAdd(&h[e4.x >> 19], 0x10000u);
                atomicAdd(&h[e4.y >> 19], 0x10000u);
                atomicAdd(&h[e4.z >> 19], 0x10000u);
                atomicAdd(&h[e4.w >> 19], 0x10000u);
            }
            if (threadIdx.x < hi - i1)
                atomicAdd(&h[dstP[s0 + i1 + threadIdx.x] >> 19], 0x10000u);
        }
    }
    // deg_out from srcP (4-wide ILP via 8B loads)
    {
        unsigned cS = curS[b * CSTR] - s0;
        unsigned lo = (unsigned)(((unsigned long long)cS * (unsigned)j) >> Jlg);
        unsigned hi = (unsigned)(((unsigned long long)cS * (unsigned)(j + 1)) >> Jlg);
        unsigned i0 = (lo + 3u) & ~3u;
        unsigned i1 = hi & ~3u;
        if (i0 >= i1) {
            for (unsigned i = lo + threadIdx.x; i < hi; i += DTB)
                atomicAdd(&h[__builtin_nontemporal_load(&srcP[s0 + i])], 1u);
        } else {
            if (threadIdx.x < i0 - lo)
                atomicAdd(&h[srcP[s0 + lo + threadIdx.x]], 1u);
            const uint2v* qp = (const uint2v*)(srcP + s0);
            for (unsigned q = i0 / 4u + threadIdx.x; q < i1 / 4u; q += DTB) {
                uint2v e2 = __builtin_nontemporal_load(qp + q);
                atomicAdd(&h[e2.x & 0xFFFFu], 1u);
                atomicAdd(&h[e2.x >> 16], 1u);
                atomicAdd(&h[e2.y & 0xFFFFu], 1u);
                atomicAdd(&h[e2.y >> 16], 1u);
            }
            if (threadIdx.x < hi - i1)
                atomicAdd(&h[srcP[s0 + i1 + threadIdx.x]], 1u);
        }
    }
    __syncthreads();
    uint4v* rowv = (uint4v*)(pDeg + (size_t)blockIdx.x * BNODES);
    uint4v* hv = (uint4v*)h;
    for (int t = threadIdx.x; t < BNODES / 4; t += DTB) rowv[t] = hv[t];
}

__global__ void prep_kernel(const unsigned* __restrict__ pDeg,
                            float* __restrict__ pio, float* __restrict__ h0s,
                            float* __restrict__ isiA, int Jlg, int Npad) {
    int i = blockIdx.x * TB + threadIdx.x;
    if (i >= Npad) return;
    int b = i >> BSH, l = i & (BNODES - 1);
    int J = 1 << Jlg;
    unsigned sum = 0;
    for (int j = 0; j < J; ++j)
        sum += __builtin_nontemporal_load(&pDeg[(size_t)((b << Jlg) + j) * BNODES + l]);
    float din = (float)(sum >> 16), dout = (float)(sum & 0xFFFFu);
    float a  = 1.0f / sqrtf(fmaxf(din, 1.0f));    // inv_sqrt_in
    float bo = 1.0f / sqrtf(fmaxf(dout, 1.0f));   // inv_sqrt_out
    pio[i]  = a * bo;
    h0s[i]  = din * bo;   // invalid pad nodes: din=0 -> 0, contribute nothing
    isiA[i] = a;
}

// Weighted histogram over dstP: h[dst_local] += table[src].
// LAST=1 marks the final consumer of dstP (nt-load).
template <int LAST>
__global__ void wh_kernel(const unsigned* __restrict__ dstP, const unsigned* __restrict__ curD,
                          unsigned CAP, const float* __restrict__ table,
                          float* __restrict__ pOut, int Jlg) {
    __shared__ float h[BNODES];
    {
        float4v* hv = (float4v*)h;
        for (int t = threadIdx.x; t < BNODES / 4; t += DTB) hv[t] = (float4v)0.0f;
    }
    __syncthreads();
    int b = blockIdx.x >> Jlg;
    int j = blockIdx.x & ((1 << Jlg) - 1);
    unsigned s0 = (unsigned)b * CAP;
    unsigned cD = curD[b * CSTR] - s0;
    unsigned lo = (unsigned)(((unsigned long long)cD * (unsigned)j) >> Jlg);
    unsigned hi = (unsigned)(((unsigned long long)cD * (unsigned)(j + 1)) >> Jlg);
    unsigned i0 = (lo + 3u) & ~3u;
    unsigned i1 = hi & ~3u;
    if (i0 >= i1) {
        for (unsigned i = lo + threadIdx.x; i < hi; i += DTB) {
            unsigned e = dstP[s0 + i];
            atomicAdd(&h[e >> 19], table[e & 0x7FFFFu]);
        }
    } else {
        if (threadIdx.x < i0 - lo) {
            unsigned e = dstP[s0 + lo + threadIdx.x];
            atomicAdd(&h[e >> 19], table[e & 0x7FFFFu]);
        }
        const uint4v* qp = (const uint4v*)(dstP + s0);
        for (unsigned q = i0 / 4u + threadIdx.x; q < i1 / 4u; q += DTB) {
            uint4v e4 = LAST ? __builtin_nontemporal_load(qp + q) : qp[q];
            float t0 = table[e4.x & 0x7FFFFu];
            float t1 = table[e4.y & 0x7FFFFu];
            float t2 = table[e4.z & 0x7FFFFu];
            float t3 = table[e4.w & 0x7FFFFu];
            atomicAdd(&h[e4.x >> 19], t0);
            atomicAdd(&h[e4.y >> 19], t1);
            atomicAdd(&h[e4.z >> 19], t2);
            atomicAdd(&h[e4.w >> 19], t3);
        }
        if (threadIdx.x < hi - i1) {
            unsigned e = dstP[s0 + i1 + threadIdx.x];
            atomicAdd(&h[e >> 19], table[e & 0x7FFFFu]);
        }
    }
    __syncthreads();
    float4v* rowv = (float4v*)(pOut + (size_t)blockIdx.x * BNODES);
    float4v* hv = (float4v*)h;
    for (int t = threadIdx.x; t < BNODES / 4; t += DTB) rowv[t] = hv[t];
}

__global__ void mid_kernel(const float* __restrict__ pC, const float* __restrict__ pio,
                           float* __restrict__ sarr, int Jlg, int Npad) {
    int i = blockIdx.x * TB + threadIdx.x;
    if (i >= Npad) return;
    int b = i >> BSH, l = i & (BNODES - 1);
    int J = 1 << Jlg;
    float t1 = 0.0f;
    for (int j = 0; j < J; ++j)
        t1 += __builtin_nontemporal_load(&pC[(size_t)((b << Jlg) + j) * BNODES + l]);
    sarr[i] = t1 * pio[i];   // normal store: sarr is wh2's random-read table, keep cached
}

__global__ void poolfinal_kernel(const float* __restrict__ pT, const float* __restrict__ isiA,
                                 const int* __restrict__ graph_ids,
                                 float* __restrict__ Xsum, int Jlg, int N) {
    int i = blockIdx.x * TB + threadIdx.x;
    bool valid = i < N;
    int ii = valid ? i : (N - 1);
    int b = ii >> BSH, l = ii & (BNODES - 1);
    int J = 1 << Jlg;
    float t2 = 0.0f;
    for (int j = 0; j < J; ++j)
        t2 += __builtin_nontemporal_load(&pT[(size_t)((b << Jlg) + j) * BNODES + l]);
    float x = valid ? t2 * isiA[ii] : 0.0f;
    int g = graph_ids[ii];
    int g0 = __shfl(g, 0, 64);
    bool uniform = __all((!valid) || (g == g0));
    if (uniform) {
#pragma unroll
        for (int off = 32; off >= 1; off >>= 1) x += __shfl_down(x, off, 64);
        if ((threadIdx.x & 63) == 0) atomicAdd(&Xsum[g0], x);
    } else if (valid) {
        atomicAdd(&Xsum[g], x);
    }
}

__global__ void final_kernel(const float* __restrict__ Xsum, const int* __restrict__ graph_ids,
                             const float* __restrict__ W1, const float* __restrict__ W2,
                             const float* __restrict__ Wlast,
                             float* __restrict__ out, int N, int GC) {
    int i = blockIdx.x * TB + threadIdx.x;
    if (i < GC) {
        int g = i >> 3, j = i & 7;
        int lo = 0, hi = N;
        while (lo < hi) { int m = (lo + hi) >> 1; if (graph_ids[m] < g) lo = m + 1; else hi = m; }
        int lo2 = lo, hi2 = N;
        while (lo2 < hi2) { int m = (lo2 + hi2) >> 1; if (graph_ids[m] < g + 1) lo2 = m + 1; else hi2 = m; }
        float c = (float)(lo2 - lo);
        float r = 0.0f;
#pragma unroll
        for (int cc = 0; cc < 8; ++cc) {
            float m = 0.0f;
#pragma unroll
            for (int k = 0; k < 8; ++k) m += fmaxf(W1[k], 0.0f) * W2[k * 8 + cc];
            r += fmaxf(m, 0.0f) * Wlast[cc * 8 + j];
        }
        out[i] = Xsum[g] / fmaxf(c, 1.0f) * r;
    }
}

// ---------------- fallback (atomic) path ----------------

__global__ void fb_deg_kernel(const int* __restrict__ src, const int* __restrict__ dst,
                              float* __restrict__ deg_out, float* __restrict__ deg_in, int E) {
    int i = blockIdx.x * TB + threadIdx.x;
    if (i < E) {
        atomicAdd(&deg_out[src[i]], 1.0f);
        atomicAdd(&deg_in[dst[i]], 1.0f);
    }
}

__global__ void fb_prep_kernel(const float* __restrict__ deg_in, const float* __restrict__ deg_out,
                               float* __restrict__ isi, float* __restrict__ iso,
                               float* __restrict__ h0s, int N) {
    int i = blockIdx.x * TB + threadIdx.x;
    if (i < N) {
        float di = deg_in[i], dn = deg_out[i];
        float a = 1.0f / sqrtf(fmaxf(di, 1.0f));
        float b = 1.0f / sqrtf(fmaxf(dn, 1.0f));
        isi[i] = a; iso[i] = b; h0s[i] = di * b;
    }
}

__global__ void fb_conv_kernel(const int* __restrict__ src, const int* __restrict__ dst,
                               const float* __restrict__ vals, float* __restrict__ t, int E) {
    int i = blockIdx.x * TB + threadIdx.x;
    if (i < E) atomicAdd(&t[dst[i]], vals[src[i]]);
}

__global__ void fb_mid_kernel(const float* __restrict__ agg1, const float* __restrict__ isi,
                              const float* __restrict__ iso, float* __restrict__ s, int N) {
    int i = blockIdx.x * TB + threadIdx.x;
    if (i < N) s[i] = agg1[i] * isi[i] * iso[i];
}

__global__ void fb_pool_kernel(const float* __restrict__ t2, const float* __restrict__ isi,
                               const int* __restrict__ graph_ids,
                               float* __restrict__ Xsum, float* __restrict__ counts, int N) {
    int i = blockIdx.x * TB + threadIdx.x;
    bool valid = i < N;
    int ii = valid ? i : (N - 1);
    float x = valid ? t2[ii] * isi[ii] : 0.0f;
    float cnt = valid ? 1.0f : 0.0f;
    int g = graph_ids[ii];
    int g0 = __shfl(g, 0, 64);
    bool uniform = __all((!valid) || (g == g0));
    if (uniform) {
#pragma unroll
        for (int off = 32; off >= 1; off >>= 1) {
            x += __shfl_down(x, off, 64);
            cnt += __shfl_down(cnt, off, 64);
        }
        if ((threadIdx.x & 63) == 0) { atomicAdd(&Xsum[g0], x); atomicAdd(&counts[g0], cnt); }
    } else if (valid) {
        atomicAdd(&Xsum[g], x); atomicAdd(&counts[g], 1.0f);
    }
}

__global__ void fb_final_kernel(const float* __restrict__ Xsum, const float* __restrict__ counts,
                                const float* __restrict__ W1, const float* __restrict__ W2,
                                const float* __restrict__ Wlast, float* __restrict__ out, int GC) {
    int i = blockIdx.x * TB + threadIdx.x;
    if (i < GC) {
        int g = i >> 3, j = i & 7;
        float r = 0.0f;
#pragma unroll
        for (int c = 0; c < 8; ++c) {
            float m = 0.0f;
#pragma unroll
            for (int k = 0; k < 8; ++k) m += fmaxf(W1[k], 0.0f) * W2[k * 8 + c];
            r += fmaxf(m, 0.0f) * Wlast[c * 8 + j];
        }
        out[i] = Xsum[g] / fmaxf(counts[g], 1.0f) * r;
    }
}

// ---------------- launch ----------------

extern "C" void kernel_launch(void* const* d_in, const int* in_sizes, int n_in,
                              void* d_out, int out_size, void* d_ws, size_t ws_size,
                              hipStream_t stream) {
    const float* W1        = (const float*)d_in[0];
    const float* W2        = (const float*)d_in[1];
    const float* Wlast     = (const float*)d_in[2];
    const int*   src       = (const int*)d_in[3];
    const int*   dst       = (const int*)d_in[4];
    const int*   graph_ids = (const int*)d_in[5];
    float* out = (float*)d_out;

    const int E = in_sizes[3];
    const int N = in_sizes[5];
    const int G = out_size / 8;

    int NB   = (N + BNODES - 1) >> BSH;
    int Npad = NB << BSH;
    int NCH  = (E + SCH - 1) / SCH;
    // Per-bucket capacity: mean + 8192 (~20 sigma for E=10M random), 512-aligned.
    unsigned CAP = (unsigned)(((E / (NB > 0 ? NB : 1)) + 8192 + 511) & ~511);

    // Pick largest J in {16,8,4,2,1} whose layout fits ws.
    int Jlg = 4;
    size_t req = 0;
    size_t o_dstP, o_srcP, o_curD, o_curS, o_part, o_pio, o_h0sar, o_isi, o_Xsum;
    for (;; --Jlg) {
        int J = 1 << Jlg;
        size_t off = 0;
        auto A = [&](size_t bytes) { size_t o = off; off = (off + bytes + 127) & ~(size_t)127; return o; };
        o_dstP  = A((size_t)NB * CAP * 4);
        o_srcP  = A((size_t)NB * CAP * 2);
        o_curD  = A((size_t)NB * CSTR * 4);
        o_curS  = A((size_t)NB * CSTR * 4);
        o_part  = A((size_t)NB * J * BNODES * 4);  // pDeg -> pC -> pT (aliased)
        o_pio   = A((size_t)Npad * 4);
        o_h0sar = A((size_t)Npad * 4);             // h0s -> sarr (aliased)
        o_isi   = A((size_t)Npad * 4);
        o_Xsum  = A((size_t)G * 4);
        req = off;
        if (req <= ws_size || Jlg == 0) break;
    }

    bool fast = (N <= (1 << 19)) && (NB <= MAXNB) && (ws_size >= req) && (E >= 1);

    char* bp = (char*)d_ws;

    if (fast) {
        unsigned*       dstP = (unsigned*)(bp + o_dstP);
        unsigned short* srcP = (unsigned short*)(bp + o_srcP);
        unsigned* curD = (unsigned*)(bp + o_curD);
        unsigned* curS = (unsigned*)(bp + o_curS);
        unsigned* pDeg = (unsigned*)(bp + o_part);
        float*    pC   = (float*)(bp + o_part);
        float*    pT   = (float*)(bp + o_part);
        float* pio  = (float*)(bp + o_pio);
        float* h0s  = (float*)(bp + o_h0sar);
        float* sarr = (float*)(bp + o_h0sar);
        float* isiA = (float*)(bp + o_isi);
        float* Xsum = (float*)(bp + o_Xsum);

        int gridNp = (Npad + TB - 1) / TB;
        int gridN  = (N + TB - 1) / TB;
        int J = 1 << Jlg;
        int gridI = (max(NB, G) + TB - 1) / TB;

        int NCH1 = (NCH + 1) / 2;
        int NCH2 = NCH - NCH1;

        init_kernel<<<gridI, TB, 0, stream>>>(curD, curS, Xsum, NB, CAP, G);
        scatter_sort_kernel<<<NCH1, STB, 0, stream>>>(src, dst, curD, curS, dstP, srcP, NB, E, 0);
        if (NCH2 > 0)
            scatter_sort_kernel<<<NCH2, STB, 0, stream>>>(src, dst, curD, curS, dstP, srcP, NB, E, NCH1);
        deghist_kernel<<<NB * J, DTB, 0, stream>>>(srcP, dstP, curS, curD, CAP, pDeg, Jlg);
        prep_kernel<<<gridNp, TB, 0, stream>>>(pDeg, pio, h0s, isiA, Jlg, Npad);
        wh_kernel<0><<<NB * J, DTB, 0, stream>>>(dstP, curD, CAP, h0s, pC, Jlg);
        mid_kernel<<<gridNp, TB, 0, stream>>>(pC, pio, sarr, Jlg, Npad);
        wh_kernel<1><<<NB * J, DTB, 0, stream>>>(dstP, curD, CAP, sarr, pT, Jlg);
        poolfinal_kernel<<<gridN, TB, 0, stream>>>(pT, isiA, graph_ids, Xsum, Jlg, N);
        final_kernel<<<(out_size + TB - 1) / TB, TB, 0, stream>>>(Xsum, graph_ids,
                                                                  W1, W2, Wlast, out, N, out_size);
    } else {
        float* ws = (float*)d_ws;
        size_t f = 0;
        auto FA = [&](size_t n) { size_t o = f; f += (n + 3) & ~(size_t)3; return o; };
        size_t f_degin  = FA(N);
        size_t f_degout = FA(N);
        size_t f_agg1   = FA(N);
        size_t f_t2     = FA(N);
        size_t f_Xsum   = FA(G);
        size_t f_cnt    = FA(G);
        size_t zf = f;
        size_t f_isi = FA(N);
        size_t f_iso = FA(N);
        size_t f_h0s = FA(N);
        size_t f_s   = FA(N);
        hipMemsetAsync(ws, 0, zf * sizeof(float), stream);
        int gridE = (E + TB - 1) / TB;
        int gridN = (N + TB - 1) / TB;
        int gridO = (out_size + TB - 1) / TB;
        fb_deg_kernel<<<gridE, TB, 0, stream>>>(src, dst, ws + f_degout, ws + f_degin, E);
        fb_prep_kernel<<<gridN, TB, 0, stream>>>(ws + f_degin, ws + f_degout,
                                                 ws + f_isi, ws + f_iso, ws + f_h0s, N);
        fb_conv_kernel<<<gridE, TB, 0, stream>>>(src, dst, ws + f_h0s, ws + f_agg1, E);
        fb_mid_kernel<<<gridN, TB, 0, stream>>>(ws + f_agg1, ws + f_isi, ws + f_iso, ws + f_s, N);
        fb_conv_kernel<<<gridE, TB, 0, stream>>>(src, dst, ws + f_s, ws + f_t2, E);
        fb_pool_kernel<<<gridN, TB, 0, stream>>>(ws + f_t2, ws + f_isi, graph_ids,
                                                 ws + f_Xsum, ws + f_cnt, N);
        fb_final_kernel<<<gridO, TB, 0, stream>>>(ws + f_Xsum, ws + f_cnt, W1, W2, Wlast,
                                                  out, out_size);
    }
}